// Round 5
// baseline (228.567 us; speedup 1.0000x reference)
//
#include <hip/hip_runtime.h>

#define B 8
#define E 2000
#define NTRI 10000
#define NRELS 25
#define KT 16
#define TT 3
#define LL 32
#define TAU1 10.0f
#define XBLK 8192
#define XTHR 256

__device__ __forceinline__ float clip01(float x) { return fminf(fmaxf(x, 0.0f), 1.0f); }

__device__ __forceinline__ void proc_e2t(float4 v, int i, unsigned int* __restrict__ packed) {
    if (v.x == 0.f && v.y == 0.f && v.z == 0.f && v.w == 0.f) return;
    int f = i * 4;
    float c[4] = {v.x, v.y, v.z, v.w};
#pragma unroll
    for (int k = 0; k < 4; k++)
        if (c[k] != 0.f) {
            int a = f + k;
            int head = a / NTRI;
            int j = a - head * NTRI;
            atomicOr(&packed[j], (unsigned int)head);
        }
}

__device__ __forceinline__ void proc_t2e(float4 v, int i, unsigned int* __restrict__ packed) {
    if (v.x == 0.f && v.y == 0.f && v.z == 0.f && v.w == 0.f) return;
    int f = i * 4;
    float c[4] = {v.x, v.y, v.z, v.w};
#pragma unroll
    for (int k = 0; k < 4; k++)
        if (c[k] != 0.f) {
            int a = f + k;
            int j = a / E;
            unsigned int tail = a - j * E;
            atomicOr(&packed[j], tail << 11);
        }
}

// One pass over all dense one-hots; no data-dependent loads, and the two 80 MB
// sweeps are interleaved + x2 unrolled so each thread has 4 independent float4
// loads in flight before any use (beats the per-iter vmcnt(0) serialization
// that capped R4 at ~2.9 TB/s logical read).
// packed[j] = head | tail<<11 | rel<<22.
__global__ void __launch_bounds__(XTHR) extract_all(
        const float4* __restrict__ e2t, const float4* __restrict__ t2e,
        const float4* __restrict__ t2r, const float4* __restrict__ ix,
        const float4* __restrict__ tm,
        unsigned int* __restrict__ packed,
        int* __restrict__ ent, int* __restrict__ tidx, float4* __restrict__ out4) {
    const int gtid = blockIdx.x * XTHR + threadIdx.x;
    const int gs = XBLK * XTHR;
    const float4 z = make_float4(0.f, 0.f, 0.f, 0.f);

    // input_x [B,E]: ent[b] = col  (4000 float4)
    for (int i = gtid; i < B * E / 4; i += gs) {
        float4 v = ix[i];
        if (v.x != 0.f || v.y != 0.f || v.z != 0.f || v.w != 0.f) {
            int f = i * 4;
            float c[4] = {v.x, v.y, v.z, v.w};
#pragma unroll
            for (int k = 0; k < 4; k++)
                if (c[k] != 0.f) { int a = f + k; int b = a / E; ent[b] = a - b * E; }
        }
    }
    // type_mat [E,KT]: tidx[e] = col  (8000 float4)
    for (int i = gtid; i < E * KT / 4; i += gs) {
        float4 v = tm[i];
        if (v.x != 0.f || v.y != 0.f || v.z != 0.f || v.w != 0.f) {
            int f = i * 4;
            float c[4] = {v.x, v.y, v.z, v.w};
#pragma unroll
            for (int k = 0; k < 4; k++)
                if (c[k] != 0.f) { int a = f + k; int e = a / KT; tidx[e] = a - e * KT; }
        }
    }
    // zero d_out (4000 float4)
    for (int i = gtid; i < B * E / 4; i += gs) out4[i] = z;

    // triple2r [NTRI,NRELS] (62500 float4): rel field
    for (int i = gtid; i < NTRI * NRELS / 4; i += gs) {
        float4 v = t2r[i];
        if (v.x != 0.f || v.y != 0.f || v.z != 0.f || v.w != 0.f) {
            int f = i * 4;
            float c[4] = {v.x, v.y, v.z, v.w};
#pragma unroll
            for (int k = 0; k < 4; k++)
                if (c[k] != 0.f) {
                    int a = f + k;
                    int j = a / NRELS;
                    unsigned int r = a - j * NRELS;
                    atomicOr(&packed[j], r << 22);
                }
        }
    }

    // e2triple + triple2e interleaved (each 5,000,000 float4), x2 unrolled:
    // 4 independent loads issued before first use.
    {
        const int n4 = E * NTRI / 4;
        for (int i0 = gtid; i0 < n4; i0 += gs * 2) {
            int i1 = i0 + gs;
            bool ok1 = (i1 < n4);
            float4 a0 = e2t[i0];
            float4 b0 = t2e[i0];
            float4 a1 = ok1 ? e2t[i1] : z;
            float4 b1 = ok1 ? t2e[i1] : z;
            proc_e2t(a0, i0, packed);
            proc_t2e(b0, i0, packed);
            proc_e2t(a1, i1, packed);
            proc_t2e(b1, i1, packed);
        }
    }
}

// One block per (b,l); all TT rounds internally, s stays in LDS.
// mask (tail-rel existence bitmask) is built per-block in LDS during the t=0
// scan of packed. t=2 fuses the l-reduction via global fp32 atomics into out.
__global__ void __launch_bounds__(512) mega_prop(
        const unsigned int* __restrict__ packed, const int* __restrict__ ent,
        const int* __restrict__ tidx,
        const float* __restrict__ w, const float* __restrict__ h,
        const float* __restrict__ h_type, const float* __restrict__ alpha,
        const float* __restrict__ beta, const float* __restrict__ h_x,
        const float* __restrict__ h_x_type, const float* __restrict__ alpha_x,
        const float* __restrict__ beta_x, const float* __restrict__ weight,
        float* __restrict__ out) {
    __shared__ float prev[E];
    __shared__ float acc[E];
    __shared__ unsigned int mask_s[E];
    __shared__ int tidx_s[E];
    __shared__ float wrow[NRELS];
    __shared__ float hp[NRELS - 1];
    __shared__ float htpL[KT];
    __shared__ unsigned int relflag;
    __shared__ float extra_s;

    const int NT = 512;
    const int blk = blockIdx.x, b = blk >> 5, l = blk & 31, tid = threadIdx.x;
    const int ent_b = ent[b];

    for (int e = tid; e < E; e += NT) {
        acc[e] = 0.f;
        mask_s[e] = 0u;
        tidx_s[e] = tidx[e];
    }
    if (tid == 0) { relflag = 0u; extra_s = 1.f; }

    const uint4* p4 = (const uint4*)packed;

    for (int t = 0; t < TT; t++) {
        const int tl = t * LL + l;
        if (tid == 0) {
            const float* wr = w + tl * NRELS;
            float mx = wr[0];
            for (int r = 1; r < NRELS; r++) mx = fmaxf(mx, wr[r]);
            float ex[NRELS], s = 0.f;
            for (int r = 0; r < NRELS; r++) { ex[r] = expf(wr[r] - mx); s += ex[r]; }
            float inv = 1.f / s;
            for (int r = 0; r < NRELS; r++) wrow[r] = ex[r] * inv;
        }
        if (tid >= 64 && tid < 64 + NRELS - 1)
            hp[tid - 64] = clip01(h[tl * (NRELS - 1) + (tid - 64)] / TAU1);
        if (tid >= 128 && tid < 128 + KT)
            htpL[tid - 128] = clip01(h_type[tl * KT + (tid - 128)] / TAU1);
        __syncthreads();

        if (t == 0) {
            for (int i = tid; i < NTRI / 4; i += NT) {
                uint4 p = p4[i];
#pragma unroll
                for (int k = 0; k < 4; k++) {
                    unsigned int pk = (k == 0) ? p.x : (k == 1) ? p.y : (k == 2) ? p.z : p.w;
                    unsigned int r = pk >> 22;
                    int tail = (pk >> 11) & 2047;
                    if (r < NRELS - 1) atomicOr(&mask_s[tail], 1u << r);  // hidden_base flags
                    if ((int)(pk & 2047u) == ent_b) {
                        atomicAdd(&acc[tail], wrow[r]);
                        atomicOr(&relflag, 1u << r);
                    }
                }
            }
        } else {
            for (int i = tid; i < NTRI / 4; i += NT) {
                uint4 p = p4[i];
#pragma unroll
                for (int k = 0; k < 4; k++) {
                    unsigned int pk = (k == 0) ? p.x : (k == 1) ? p.y : (k == 2) ? p.z : p.w;
                    float pv = prev[pk & 2047u];
                    if (pv != 0.f) {
                        unsigned int r = pk >> 22;
                        int tail = (pk >> 11) & 2047;
                        atomicAdd(&acc[tail], pv * wrow[r]);
                    }
                }
            }
        }
        __syncthreads();

        const float a = clip01(alpha[tl] / TAU1);
        const float bb = clip01(beta[tl] / TAU1);
        const float base = 1.f - clip01(a + bb);

        if (t == 0 && tid == 0) {
            unsigned int fl = relflag;
            float hxlin = 0.f;
            for (int i = 0; i < NRELS - 1; i++) {
                int pi = (i < 12) ? (12 + i) : (i - 12);  // concat(hx_raw[:,12:24], hx_raw[:,0:12])
                if ((fl >> pi) & 1u) hxlin += clip01(h_x[l * (NRELS - 1) + i] / TAU1);
            }
            float htx = clip01(h_x_type[l * KT + tidx_s[ent_b]] / TAU1);
            float ax = clip01(alpha_x[l] / TAU1), bx = clip01(beta_x[l] / TAU1);
            extra_s = clip01(a * htx + bb * hxlin) + (1.f - clip01(ax + bx));
        }
        __syncthreads();

        const float extra = (t == 0) ? extra_s : 1.f;

        if (t < TT - 1) {
            for (int e = tid; e < E; e += NT) {
                unsigned int m = mask_s[e];
                float dot = 0.f;
#pragma unroll
                for (int i = 0; i < NRELS - 1; i++) dot += ((m >> i) & 1u) ? hp[i] : 0.f;
                float he = clip01(a * htpL[tidx_s[e]] + bb * dot) + base;
                prev[e] = acc[e] * he * extra;
                acc[e] = 0.f;
            }
        } else {
            float tw = tanhf(weight[l]);
            for (int e = tid; e < E; e += NT) {
                unsigned int m = mask_s[e];
                float dot = 0.f;
#pragma unroll
                for (int i = 0; i < NRELS - 1; i++) dot += ((m >> i) & 1u) ? hp[i] : 0.f;
                float he = clip01(a * htpL[tidx_s[e]] + bb * dot) + base;
                atomicAdd(&out[b * E + e], acc[e] * he * tw);
            }
        }
        __syncthreads();
    }
}

extern "C" void kernel_launch(void* const* d_in, const int* in_sizes, int n_in,
                              void* d_out, int out_size, void* d_ws, size_t ws_size,
                              hipStream_t stream) {
    const float* input_x  = (const float*)d_in[0];
    const float* type_mat = (const float*)d_in[1];
    const float* e2triple = (const float*)d_in[2];
    const float* triple2e = (const float*)d_in[3];
    const float* triple2r = (const float*)d_in[4];
    const float* w        = (const float*)d_in[5];
    const float* weight   = (const float*)d_in[6];
    const float* h        = (const float*)d_in[7];
    const float* h_x      = (const float*)d_in[8];
    const float* h_type   = (const float*)d_in[9];
    const float* h_x_type = (const float*)d_in[10];
    const float* alpha    = (const float*)d_in[11];
    const float* beta     = (const float*)d_in[12];
    const float* alpha_x  = (const float*)d_in[13];
    const float* beta_x   = (const float*)d_in[14];
    (void)in_sizes; (void)n_in; (void)out_size; (void)ws_size;

    char* ws = (char*)d_ws;
    unsigned int* packed = (unsigned int*)ws;                    // NTRI u32, must be 0
    int* ent  = (int*)(ws + ((NTRI * 4 + 255) & ~255));
    int* tidx = ent + 64;

    hipMemsetAsync(packed, 0, NTRI * sizeof(unsigned int), stream);

    extract_all<<<XBLK, XTHR, 0, stream>>>((const float4*)e2triple, (const float4*)triple2e,
                                           (const float4*)triple2r, (const float4*)input_x,
                                           (const float4*)type_mat,
                                           packed, ent, tidx, (float4*)d_out);

    mega_prop<<<B * LL, 512, 0, stream>>>(packed, ent, tidx, w, h, h_type,
                                          alpha, beta, h_x, h_x_type, alpha_x, beta_x,
                                          weight, (float*)d_out);
}

// Round 6
// 225.634 us; speedup vs baseline: 1.0130x; 1.0130x over previous
//
#include <hip/hip_runtime.h>

#define B 8
#define E 2000
#define NTRI 10000
#define NRELS 25
#define KT 16
#define TT 3
#define LL 32
#define TAU1 10.0f
#define XBLK 8192
#define XTHR 256

__device__ __forceinline__ float clip01(float x) { return fminf(fmaxf(x, 0.0f), 1.0f); }

// One pass over all dense one-hots. packed[j] = head | tail<<11 | rel<<22.
// Big sweeps: each thread owns 64 consecutive bytes (4 float4s) per iteration,
// so the wave's first load instruction demands a full 4 KB contiguous span
// (64 whole cache lines) instead of 1 KB spread over 16 lines — bigger
// DRAM-level demand per issued instruction; the other 3 loads are L1 hits.
__global__ void __launch_bounds__(XTHR) extract_all(
        const float4* __restrict__ e2t, const float4* __restrict__ t2e,
        const float4* __restrict__ t2r, const float4* __restrict__ ix,
        const float4* __restrict__ tm,
        unsigned int* __restrict__ packed,
        int* __restrict__ ent, int* __restrict__ tidx, float4* __restrict__ out4) {
    const int gtid = blockIdx.x * XTHR + threadIdx.x;
    const int gs = XBLK * XTHR;

    // input_x [B,E]: ent[b] = col  (4000 float4)
    for (int i = gtid; i < B * E / 4; i += gs) {
        float4 v = ix[i];
        if (v.x != 0.f || v.y != 0.f || v.z != 0.f || v.w != 0.f) {
            int f = i * 4;
            float c[4] = {v.x, v.y, v.z, v.w};
#pragma unroll
            for (int k = 0; k < 4; k++)
                if (c[k] != 0.f) { int a = f + k; int b = a / E; ent[b] = a - b * E; }
        }
    }
    // type_mat [E,KT]: tidx[e] = col  (8000 float4)
    for (int i = gtid; i < E * KT / 4; i += gs) {
        float4 v = tm[i];
        if (v.x != 0.f || v.y != 0.f || v.z != 0.f || v.w != 0.f) {
            int f = i * 4;
            float c[4] = {v.x, v.y, v.z, v.w};
#pragma unroll
            for (int k = 0; k < 4; k++)
                if (c[k] != 0.f) { int a = f + k; int e = a / KT; tidx[e] = a - e * KT; }
        }
    }
    // zero d_out (4000 float4)
    float4 z = make_float4(0.f, 0.f, 0.f, 0.f);
    for (int i = gtid; i < B * E / 4; i += gs) out4[i] = z;

    // triple2r [NTRI,NRELS]: rel field. 62500 float4 -> 15625 4-float4 segments.
    for (int seg = gtid; seg < NTRI * NRELS / 16; seg += gs) {
        int i = seg * 4;
        float4 v0 = t2r[i], v1 = t2r[i + 1], v2 = t2r[i + 2], v3 = t2r[i + 3];
        float c[16] = {v0.x, v0.y, v0.z, v0.w, v1.x, v1.y, v1.z, v1.w,
                       v2.x, v2.y, v2.z, v2.w, v3.x, v3.y, v3.z, v3.w};
#pragma unroll
        for (int k = 0; k < 16; k++)
            if (c[k] != 0.f) {
                int a = i * 4 + k;
                int j = a / NRELS;
                unsigned int r = a - j * NRELS;
                atomicOr(&packed[j], r << 22);
            }
    }
    // e2triple [E,NTRI]: head field. 5,000,000 float4 -> 1,250,000 segments.
    for (int seg = gtid; seg < E * NTRI / 16; seg += gs) {
        int i = seg * 4;
        float4 v0 = e2t[i], v1 = e2t[i + 1], v2 = e2t[i + 2], v3 = e2t[i + 3];
        float c[16] = {v0.x, v0.y, v0.z, v0.w, v1.x, v1.y, v1.z, v1.w,
                       v2.x, v2.y, v2.z, v2.w, v3.x, v3.y, v3.z, v3.w};
        if (c[0] != 0.f || c[1] != 0.f || c[2] != 0.f || c[3] != 0.f ||
            c[4] != 0.f || c[5] != 0.f || c[6] != 0.f || c[7] != 0.f ||
            c[8] != 0.f || c[9] != 0.f || c[10] != 0.f || c[11] != 0.f ||
            c[12] != 0.f || c[13] != 0.f || c[14] != 0.f || c[15] != 0.f) {
#pragma unroll
            for (int k = 0; k < 16; k++)
                if (c[k] != 0.f) {
                    int a = i * 4 + k;
                    int head = a / NTRI;
                    int j = a - head * NTRI;
                    atomicOr(&packed[j], (unsigned int)head);
                }
        }
    }
    // triple2e [NTRI,E]: tail field. 1,250,000 segments.
    for (int seg = gtid; seg < NTRI * E / 16; seg += gs) {
        int i = seg * 4;
        float4 v0 = t2e[i], v1 = t2e[i + 1], v2 = t2e[i + 2], v3 = t2e[i + 3];
        float c[16] = {v0.x, v0.y, v0.z, v0.w, v1.x, v1.y, v1.z, v1.w,
                       v2.x, v2.y, v2.z, v2.w, v3.x, v3.y, v3.z, v3.w};
        if (c[0] != 0.f || c[1] != 0.f || c[2] != 0.f || c[3] != 0.f ||
            c[4] != 0.f || c[5] != 0.f || c[6] != 0.f || c[7] != 0.f ||
            c[8] != 0.f || c[9] != 0.f || c[10] != 0.f || c[11] != 0.f ||
            c[12] != 0.f || c[13] != 0.f || c[14] != 0.f || c[15] != 0.f) {
#pragma unroll
            for (int k = 0; k < 16; k++)
                if (c[k] != 0.f) {
                    int a = i * 4 + k;
                    int j = a / E;
                    unsigned int tail = a - j * E;
                    atomicOr(&packed[j], tail << 11);
                }
        }
    }
}

// One block per (b,l); all TT rounds internally, s stays in LDS.
// mask (tail-rel existence bitmask) is built per-block in LDS during the t=0
// scan of packed. t=2 fuses the l-reduction via global fp32 atomics into out.
__global__ void __launch_bounds__(512) mega_prop(
        const unsigned int* __restrict__ packed, const int* __restrict__ ent,
        const int* __restrict__ tidx,
        const float* __restrict__ w, const float* __restrict__ h,
        const float* __restrict__ h_type, const float* __restrict__ alpha,
        const float* __restrict__ beta, const float* __restrict__ h_x,
        const float* __restrict__ h_x_type, const float* __restrict__ alpha_x,
        const float* __restrict__ beta_x, const float* __restrict__ weight,
        float* __restrict__ out) {
    __shared__ float prev[E];
    __shared__ float acc[E];
    __shared__ unsigned int mask_s[E];
    __shared__ int tidx_s[E];
    __shared__ float wrow[NRELS];
    __shared__ float hp[NRELS - 1];
    __shared__ float htpL[KT];
    __shared__ unsigned int relflag;
    __shared__ float extra_s;

    const int NT = 512;
    const int blk = blockIdx.x, b = blk >> 5, l = blk & 31, tid = threadIdx.x;
    const int ent_b = ent[b];

    for (int e = tid; e < E; e += NT) {
        acc[e] = 0.f;
        mask_s[e] = 0u;
        tidx_s[e] = tidx[e];
    }
    if (tid == 0) { relflag = 0u; extra_s = 1.f; }

    const uint4* p4 = (const uint4*)packed;

    for (int t = 0; t < TT; t++) {
        const int tl = t * LL + l;
        if (tid == 0) {
            const float* wr = w + tl * NRELS;
            float mx = wr[0];
            for (int r = 1; r < NRELS; r++) mx = fmaxf(mx, wr[r]);
            float ex[NRELS], s = 0.f;
            for (int r = 0; r < NRELS; r++) { ex[r] = expf(wr[r] - mx); s += ex[r]; }
            float inv = 1.f / s;
            for (int r = 0; r < NRELS; r++) wrow[r] = ex[r] * inv;
        }
        if (tid >= 64 && tid < 64 + NRELS - 1)
            hp[tid - 64] = clip01(h[tl * (NRELS - 1) + (tid - 64)] / TAU1);
        if (tid >= 128 && tid < 128 + KT)
            htpL[tid - 128] = clip01(h_type[tl * KT + (tid - 128)] / TAU1);
        __syncthreads();

        if (t == 0) {
            for (int i = tid; i < NTRI / 4; i += NT) {
                uint4 p = p4[i];
#pragma unroll
                for (int k = 0; k < 4; k++) {
                    unsigned int pk = (k == 0) ? p.x : (k == 1) ? p.y : (k == 2) ? p.z : p.w;
                    unsigned int r = pk >> 22;
                    int tail = (pk >> 11) & 2047;
                    if (r < NRELS - 1) atomicOr(&mask_s[tail], 1u << r);  // hidden_base flags
                    if ((int)(pk & 2047u) == ent_b) {
                        atomicAdd(&acc[tail], wrow[r]);
                        atomicOr(&relflag, 1u << r);
                    }
                }
            }
        } else {
            for (int i = tid; i < NTRI / 4; i += NT) {
                uint4 p = p4[i];
#pragma unroll
                for (int k = 0; k < 4; k++) {
                    unsigned int pk = (k == 0) ? p.x : (k == 1) ? p.y : (k == 2) ? p.z : p.w;
                    float pv = prev[pk & 2047u];
                    if (pv != 0.f) {
                        unsigned int r = pk >> 22;
                        int tail = (pk >> 11) & 2047;
                        atomicAdd(&acc[tail], pv * wrow[r]);
                    }
                }
            }
        }
        __syncthreads();

        const float a = clip01(alpha[tl] / TAU1);
        const float bb = clip01(beta[tl] / TAU1);
        const float base = 1.f - clip01(a + bb);

        if (t == 0 && tid == 0) {
            unsigned int fl = relflag;
            float hxlin = 0.f;
            for (int i = 0; i < NRELS - 1; i++) {
                int pi = (i < 12) ? (12 + i) : (i - 12);  // concat(hx_raw[:,12:24], hx_raw[:,0:12])
                if ((fl >> pi) & 1u) hxlin += clip01(h_x[l * (NRELS - 1) + i] / TAU1);
            }
            float htx = clip01(h_x_type[l * KT + tidx_s[ent_b]] / TAU1);
            float ax = clip01(alpha_x[l] / TAU1), bx = clip01(beta_x[l] / TAU1);
            extra_s = clip01(a * htx + bb * hxlin) + (1.f - clip01(ax + bx));
        }
        __syncthreads();

        const float extra = (t == 0) ? extra_s : 1.f;

        if (t < TT - 1) {
            for (int e = tid; e < E; e += NT) {
                unsigned int m = mask_s[e];
                float dot = 0.f;
#pragma unroll
                for (int i = 0; i < NRELS - 1; i++) dot += ((m >> i) & 1u) ? hp[i] : 0.f;
                float he = clip01(a * htpL[tidx_s[e]] + bb * dot) + base;
                prev[e] = acc[e] * he * extra;
                acc[e] = 0.f;
            }
        } else {
            float tw = tanhf(weight[l]);
            for (int e = tid; e < E; e += NT) {
                unsigned int m = mask_s[e];
                float dot = 0.f;
#pragma unroll
                for (int i = 0; i < NRELS - 1; i++) dot += ((m >> i) & 1u) ? hp[i] : 0.f;
                float he = clip01(a * htpL[tidx_s[e]] + bb * dot) + base;
                atomicAdd(&out[b * E + e], acc[e] * he * tw);
            }
        }
        __syncthreads();
    }
}

extern "C" void kernel_launch(void* const* d_in, const int* in_sizes, int n_in,
                              void* d_out, int out_size, void* d_ws, size_t ws_size,
                              hipStream_t stream) {
    const float* input_x  = (const float*)d_in[0];
    const float* type_mat = (const float*)d_in[1];
    const float* e2triple = (const float*)d_in[2];
    const float* triple2e = (const float*)d_in[3];
    const float* triple2r = (const float*)d_in[4];
    const float* w        = (const float*)d_in[5];
    const float* weight   = (const float*)d_in[6];
    const float* h        = (const float*)d_in[7];
    const float* h_x      = (const float*)d_in[8];
    const float* h_type   = (const float*)d_in[9];
    const float* h_x_type = (const float*)d_in[10];
    const float* alpha    = (const float*)d_in[11];
    const float* beta     = (const float*)d_in[12];
    const float* alpha_x  = (const float*)d_in[13];
    const float* beta_x   = (const float*)d_in[14];
    (void)in_sizes; (void)n_in; (void)out_size; (void)ws_size;

    char* ws = (char*)d_ws;
    unsigned int* packed = (unsigned int*)ws;                    // NTRI u32, must be 0
    int* ent  = (int*)(ws + ((NTRI * 4 + 255) & ~255));
    int* tidx = ent + 64;

    hipMemsetAsync(packed, 0, NTRI * sizeof(unsigned int), stream);

    extract_all<<<XBLK, XTHR, 0, stream>>>((const float4*)e2triple, (const float4*)triple2e,
                                           (const float4*)triple2r, (const float4*)input_x,
                                           (const float4*)type_mat,
                                           packed, ent, tidx, (float4*)d_out);

    mega_prop<<<B * LL, 512, 0, stream>>>(packed, ent, tidx, w, h, h_type,
                                          alpha, beta, h_x, h_x_type, alpha_x, beta_x,
                                          weight, (float*)d_out);
}

// Round 7
// 222.896 us; speedup vs baseline: 1.0254x; 1.0123x over previous
//
#include <hip/hip_runtime.h>

#define B 8
#define E 2000
#define NTRI 10000
#define NRELS 25
#define KT 16
#define TT 3
#define LL 32
#define TAU1 10.0f
#define XBLK 8192
#define XTHR 256

__device__ __forceinline__ float clip01(float x) { return fminf(fmaxf(x, 0.0f), 1.0f); }

// One pass over all dense one-hot inputs. Every row/column involved is one-hot
// by construction, so each output slot has EXACTLY ONE writer: plain stores,
// no atomics, no pre-zero memset (saves a graph node). Loop shape = R4's
// simple grid-stride float4 (empirically best of 4 variants tried).
__global__ void __launch_bounds__(XTHR) extract_all(
        const float4* __restrict__ e2t, const float4* __restrict__ t2e,
        const float4* __restrict__ t2r, const float4* __restrict__ ix,
        const float4* __restrict__ tm,
        int* __restrict__ heads, int* __restrict__ tails, int* __restrict__ rels,
        int* __restrict__ ent, int* __restrict__ tidx, float4* __restrict__ out4) {
    const int gtid = blockIdx.x * XTHR + threadIdx.x;
    const int gs = XBLK * XTHR;

    // input_x [B,E]: ent[b] = col  (4000 float4)
    for (int i = gtid; i < B * E / 4; i += gs) {
        float4 v = ix[i];
        if (v.x != 0.f || v.y != 0.f || v.z != 0.f || v.w != 0.f) {
            int f = i * 4;
            float c[4] = {v.x, v.y, v.z, v.w};
#pragma unroll
            for (int k = 0; k < 4; k++)
                if (c[k] != 0.f) { int a = f + k; int b = a / E; ent[b] = a - b * E; }
        }
    }
    // type_mat [E,KT]: tidx[e] = col  (8000 float4)
    for (int i = gtid; i < E * KT / 4; i += gs) {
        float4 v = tm[i];
        if (v.x != 0.f || v.y != 0.f || v.z != 0.f || v.w != 0.f) {
            int f = i * 4;
            float c[4] = {v.x, v.y, v.z, v.w};
#pragma unroll
            for (int k = 0; k < 4; k++)
                if (c[k] != 0.f) { int a = f + k; int e = a / KT; tidx[e] = a - e * KT; }
        }
    }
    // zero d_out (4000 float4) so mega_prop can atomicAdd into it
    float4 z = make_float4(0.f, 0.f, 0.f, 0.f);
    for (int i = gtid; i < B * E / 4; i += gs) out4[i] = z;

    // triple2r [NTRI,NRELS] (62500 float4): rels[j]
    for (int i = gtid; i < NTRI * NRELS / 4; i += gs) {
        float4 v = t2r[i];
        if (v.x != 0.f || v.y != 0.f || v.z != 0.f || v.w != 0.f) {
            int f = i * 4;
            float c[4] = {v.x, v.y, v.z, v.w};
#pragma unroll
            for (int k = 0; k < 4; k++)
                if (c[k] != 0.f) {
                    int a = f + k;
                    int j = a / NRELS;
                    rels[j] = a - j * NRELS;
                }
        }
    }
    // e2triple [E,NTRI] (5M float4): heads[j]
    for (int i = gtid; i < E * NTRI / 4; i += gs) {
        float4 v = e2t[i];
        if (v.x != 0.f || v.y != 0.f || v.z != 0.f || v.w != 0.f) {
            int f = i * 4;
            float c[4] = {v.x, v.y, v.z, v.w};
#pragma unroll
            for (int k = 0; k < 4; k++)
                if (c[k] != 0.f) {
                    int a = f + k;
                    int head = a / NTRI;
                    heads[a - head * NTRI] = head;
                }
        }
    }
    // triple2e [NTRI,E] (5M float4): tails[j]
    for (int i = gtid; i < NTRI * E / 4; i += gs) {
        float4 v = t2e[i];
        if (v.x != 0.f || v.y != 0.f || v.z != 0.f || v.w != 0.f) {
            int f = i * 4;
            float c[4] = {v.x, v.y, v.z, v.w};
#pragma unroll
            for (int k = 0; k < 4; k++)
                if (c[k] != 0.f) {
                    int a = f + k;
                    int j = a / E;
                    tails[j] = a - j * E;
                }
        }
    }
}

// One block per (b,l); all TT rounds internally, s stays in LDS.
// mask (tail-rel existence bitmask) is built per-block in LDS during the t=0
// scan. t=2 fuses the l-reduction via global fp32 atomics into out.
__global__ void __launch_bounds__(512) mega_prop(
        const int* __restrict__ heads, const int* __restrict__ tails,
        const int* __restrict__ rels, const int* __restrict__ ent,
        const int* __restrict__ tidx,
        const float* __restrict__ w, const float* __restrict__ h,
        const float* __restrict__ h_type, const float* __restrict__ alpha,
        const float* __restrict__ beta, const float* __restrict__ h_x,
        const float* __restrict__ h_x_type, const float* __restrict__ alpha_x,
        const float* __restrict__ beta_x, const float* __restrict__ weight,
        float* __restrict__ out) {
    __shared__ float prev[E];
    __shared__ float acc[E];
    __shared__ unsigned int mask_s[E];
    __shared__ int tidx_s[E];
    __shared__ float wrow[NRELS];
    __shared__ float hp[NRELS - 1];
    __shared__ float htpL[KT];
    __shared__ unsigned int relflag;
    __shared__ float extra_s;

    const int NT = 512;
    const int blk = blockIdx.x, b = blk >> 5, l = blk & 31, tid = threadIdx.x;
    const int ent_b = ent[b];

    for (int e = tid; e < E; e += NT) {
        acc[e] = 0.f;
        mask_s[e] = 0u;
        tidx_s[e] = tidx[e];
    }
    if (tid == 0) { relflag = 0u; extra_s = 1.f; }

    const uint4* h4 = (const uint4*)heads;
    const uint4* t4 = (const uint4*)tails;
    const uint4* r4 = (const uint4*)rels;

    for (int t = 0; t < TT; t++) {
        const int tl = t * LL + l;
        if (tid == 0) {
            const float* wr = w + tl * NRELS;
            float mx = wr[0];
            for (int r = 1; r < NRELS; r++) mx = fmaxf(mx, wr[r]);
            float ex[NRELS], s = 0.f;
            for (int r = 0; r < NRELS; r++) { ex[r] = expf(wr[r] - mx); s += ex[r]; }
            float inv = 1.f / s;
            for (int r = 0; r < NRELS; r++) wrow[r] = ex[r] * inv;
        }
        if (tid >= 64 && tid < 64 + NRELS - 1)
            hp[tid - 64] = clip01(h[tl * (NRELS - 1) + (tid - 64)] / TAU1);
        if (tid >= 128 && tid < 128 + KT)
            htpL[tid - 128] = clip01(h_type[tl * KT + (tid - 128)] / TAU1);
        __syncthreads();

        if (t == 0) {
            for (int i = tid; i < NTRI / 4; i += NT) {
                uint4 hh = h4[i], ttv = t4[i], rr = r4[i];
#pragma unroll
                for (int k = 0; k < 4; k++) {
                    unsigned int hd = (k == 0) ? hh.x : (k == 1) ? hh.y : (k == 2) ? hh.z : hh.w;
                    unsigned int ta = (k == 0) ? ttv.x : (k == 1) ? ttv.y : (k == 2) ? ttv.z : ttv.w;
                    unsigned int r  = (k == 0) ? rr.x : (k == 1) ? rr.y : (k == 2) ? rr.z : rr.w;
                    if (r < NRELS - 1) atomicOr(&mask_s[ta], 1u << r);  // hidden_base flags
                    if ((int)hd == ent_b) {
                        atomicAdd(&acc[ta], wrow[r]);
                        atomicOr(&relflag, 1u << r);
                    }
                }
            }
        } else {
            for (int i = tid; i < NTRI / 4; i += NT) {
                uint4 hh = h4[i], ttv = t4[i], rr = r4[i];
#pragma unroll
                for (int k = 0; k < 4; k++) {
                    unsigned int hd = (k == 0) ? hh.x : (k == 1) ? hh.y : (k == 2) ? hh.z : hh.w;
                    float pv = prev[hd];
                    if (pv != 0.f) {
                        unsigned int ta = (k == 0) ? ttv.x : (k == 1) ? ttv.y : (k == 2) ? ttv.z : ttv.w;
                        unsigned int r  = (k == 0) ? rr.x : (k == 1) ? rr.y : (k == 2) ? rr.z : rr.w;
                        atomicAdd(&acc[ta], pv * wrow[r]);
                    }
                }
            }
        }
        __syncthreads();

        const float a = clip01(alpha[tl] / TAU1);
        const float bb = clip01(beta[tl] / TAU1);
        const float base = 1.f - clip01(a + bb);

        if (t == 0 && tid == 0) {
            unsigned int fl = relflag;
            float hxlin = 0.f;
            for (int i = 0; i < NRELS - 1; i++) {
                int pi = (i < 12) ? (12 + i) : (i - 12);  // concat(hx_raw[:,12:24], hx_raw[:,0:12])
                if ((fl >> pi) & 1u) hxlin += clip01(h_x[l * (NRELS - 1) + i] / TAU1);
            }
            float htx = clip01(h_x_type[l * KT + tidx_s[ent_b]] / TAU1);
            float ax = clip01(alpha_x[l] / TAU1), bx = clip01(beta_x[l] / TAU1);
            extra_s = clip01(a * htx + bb * hxlin) + (1.f - clip01(ax + bx));
        }
        __syncthreads();

        const float extra = (t == 0) ? extra_s : 1.f;

        if (t < TT - 1) {
            for (int e = tid; e < E; e += NT) {
                unsigned int m = mask_s[e];
                float dot = 0.f;
#pragma unroll
                for (int i = 0; i < NRELS - 1; i++) dot += ((m >> i) & 1u) ? hp[i] : 0.f;
                float he = clip01(a * htpL[tidx_s[e]] + bb * dot) + base;
                prev[e] = acc[e] * he * extra;
                acc[e] = 0.f;
            }
        } else {
            float tw = tanhf(weight[l]);
            for (int e = tid; e < E; e += NT) {
                unsigned int m = mask_s[e];
                float dot = 0.f;
#pragma unroll
                for (int i = 0; i < NRELS - 1; i++) dot += ((m >> i) & 1u) ? hp[i] : 0.f;
                float he = clip01(a * htpL[tidx_s[e]] + bb * dot) + base;
                atomicAdd(&out[b * E + e], acc[e] * he * tw);
            }
        }
        __syncthreads();
    }
}

extern "C" void kernel_launch(void* const* d_in, const int* in_sizes, int n_in,
                              void* d_out, int out_size, void* d_ws, size_t ws_size,
                              hipStream_t stream) {
    const float* input_x  = (const float*)d_in[0];
    const float* type_mat = (const float*)d_in[1];
    const float* e2triple = (const float*)d_in[2];
    const float* triple2e = (const float*)d_in[3];
    const float* triple2r = (const float*)d_in[4];
    const float* w        = (const float*)d_in[5];
    const float* weight   = (const float*)d_in[6];
    const float* h        = (const float*)d_in[7];
    const float* h_x      = (const float*)d_in[8];
    const float* h_type   = (const float*)d_in[9];
    const float* h_x_type = (const float*)d_in[10];
    const float* alpha    = (const float*)d_in[11];
    const float* beta     = (const float*)d_in[12];
    const float* alpha_x  = (const float*)d_in[13];
    const float* beta_x   = (const float*)d_in[14];
    (void)in_sizes; (void)n_in; (void)out_size; (void)ws_size;

    // All ws arrays are fully written by extract_all before mega_prop reads
    // them (one-hot structure => every slot has exactly one writer), so no
    // memset node is needed despite the 0xAA poison.
    char* ws = (char*)d_ws;
    int* heads = (int*)ws;                         // NTRI
    int* tails = heads + ((NTRI + 63) & ~63);      // NTRI
    int* rels  = tails + ((NTRI + 63) & ~63);      // NTRI
    int* ent   = rels + ((NTRI + 63) & ~63);       // B
    int* tidx  = ent + 64;                         // E

    extract_all<<<XBLK, XTHR, 0, stream>>>((const float4*)e2triple, (const float4*)triple2e,
                                           (const float4*)triple2r, (const float4*)input_x,
                                           (const float4*)type_mat,
                                           heads, tails, rels, ent, tidx, (float4*)d_out);

    mega_prop<<<B * LL, 512, 0, stream>>>(heads, tails, rels, ent, tidx, w, h, h_type,
                                          alpha, beta, h_x, h_x_type, alpha_x, beta_x,
                                          weight, (float*)d_out);
}

// Round 8
// 213.080 us; speedup vs baseline: 1.0727x; 1.0461x over previous
//
#include <hip/hip_runtime.h>

#define B 8
#define E 2000
#define NTRI 10000
#define NRELS 25
#define KT 16
#define TT 3
#define LL 32
#define TAU1 10.0f
#define XBLK 8192
#define XTHR 256

typedef __attribute__((ext_vector_type(4))) float f32x4;

__device__ __forceinline__ float clip01(float x) { return fminf(fmaxf(x, 0.0f), 1.0f); }

// One pass over all dense one-hot inputs. Every row/column involved is one-hot
// by construction, so each output slot has EXACTLY ONE writer: plain stores,
// no atomics, no memset node. The two 80 MB sweeps use NON-TEMPORAL loads
// (single-use stream; skip cache allocation on the fetch path).
__global__ void __launch_bounds__(XTHR) extract_all(
        const f32x4* __restrict__ e2t, const f32x4* __restrict__ t2e,
        const float4* __restrict__ t2r, const float4* __restrict__ ix,
        const float4* __restrict__ tm,
        int* __restrict__ heads, int* __restrict__ tails, int* __restrict__ rels,
        int* __restrict__ ent, int* __restrict__ tidx, float4* __restrict__ out4) {
    const int gtid = blockIdx.x * XTHR + threadIdx.x;
    const int gs = XBLK * XTHR;

    // input_x [B,E]: ent[b] = col  (4000 float4)
    for (int i = gtid; i < B * E / 4; i += gs) {
        float4 v = ix[i];
        if (v.x != 0.f || v.y != 0.f || v.z != 0.f || v.w != 0.f) {
            int f = i * 4;
            float c[4] = {v.x, v.y, v.z, v.w};
#pragma unroll
            for (int k = 0; k < 4; k++)
                if (c[k] != 0.f) { int a = f + k; int b = a / E; ent[b] = a - b * E; }
        }
    }
    // type_mat [E,KT]: tidx[e] = col  (8000 float4)
    for (int i = gtid; i < E * KT / 4; i += gs) {
        float4 v = tm[i];
        if (v.x != 0.f || v.y != 0.f || v.z != 0.f || v.w != 0.f) {
            int f = i * 4;
            float c[4] = {v.x, v.y, v.z, v.w};
#pragma unroll
            for (int k = 0; k < 4; k++)
                if (c[k] != 0.f) { int a = f + k; int e = a / KT; tidx[e] = a - e * KT; }
        }
    }
    // zero d_out (4000 float4) so mega_prop can atomicAdd into it
    float4 z = make_float4(0.f, 0.f, 0.f, 0.f);
    for (int i = gtid; i < B * E / 4; i += gs) out4[i] = z;

    // triple2r [NTRI,NRELS] (62500 float4): rels[j]
    for (int i = gtid; i < NTRI * NRELS / 4; i += gs) {
        float4 v = t2r[i];
        if (v.x != 0.f || v.y != 0.f || v.z != 0.f || v.w != 0.f) {
            int f = i * 4;
            float c[4] = {v.x, v.y, v.z, v.w};
#pragma unroll
            for (int k = 0; k < 4; k++)
                if (c[k] != 0.f) {
                    int a = f + k;
                    int j = a / NRELS;
                    rels[j] = a - j * NRELS;
                }
        }
    }
    // e2triple [E,NTRI] (5M float4): heads[j]  — non-temporal stream
    for (int i = gtid; i < E * NTRI / 4; i += gs) {
        f32x4 v = __builtin_nontemporal_load(&e2t[i]);
        if (v.x != 0.f || v.y != 0.f || v.z != 0.f || v.w != 0.f) {
            int f = i * 4;
            float c[4] = {v.x, v.y, v.z, v.w};
#pragma unroll
            for (int k = 0; k < 4; k++)
                if (c[k] != 0.f) {
                    int a = f + k;
                    int head = a / NTRI;
                    heads[a - head * NTRI] = head;
                }
        }
    }
    // triple2e [NTRI,E] (5M float4): tails[j]  — non-temporal stream
    for (int i = gtid; i < NTRI * E / 4; i += gs) {
        f32x4 v = __builtin_nontemporal_load(&t2e[i]);
        if (v.x != 0.f || v.y != 0.f || v.z != 0.f || v.w != 0.f) {
            int f = i * 4;
            float c[4] = {v.x, v.y, v.z, v.w};
#pragma unroll
            for (int k = 0; k < 4; k++)
                if (c[k] != 0.f) {
                    int a = f + k;
                    int j = a / E;
                    tails[j] = a - j * E;
                }
        }
    }
}

// One block per (b,l); all TT rounds internally, s stays in LDS.
// mask (tail-rel existence bitmask) is built per-block in LDS during the t=0
// scan. t=2 fuses the l-reduction via global fp32 atomics into out.
__global__ void __launch_bounds__(512) mega_prop(
        const int* __restrict__ heads, const int* __restrict__ tails,
        const int* __restrict__ rels, const int* __restrict__ ent,
        const int* __restrict__ tidx,
        const float* __restrict__ w, const float* __restrict__ h,
        const float* __restrict__ h_type, const float* __restrict__ alpha,
        const float* __restrict__ beta, const float* __restrict__ h_x,
        const float* __restrict__ h_x_type, const float* __restrict__ alpha_x,
        const float* __restrict__ beta_x, const float* __restrict__ weight,
        float* __restrict__ out) {
    __shared__ float prev[E];
    __shared__ float acc[E];
    __shared__ unsigned int mask_s[E];
    __shared__ int tidx_s[E];
    __shared__ float wrow[NRELS];
    __shared__ float hp[NRELS - 1];
    __shared__ float htpL[KT];
    __shared__ unsigned int relflag;
    __shared__ float extra_s;

    const int NT = 512;
    const int blk = blockIdx.x, b = blk >> 5, l = blk & 31, tid = threadIdx.x;
    const int ent_b = ent[b];

    for (int e = tid; e < E; e += NT) {
        acc[e] = 0.f;
        mask_s[e] = 0u;
        tidx_s[e] = tidx[e];
    }
    if (tid == 0) { relflag = 0u; extra_s = 1.f; }

    const uint4* h4 = (const uint4*)heads;
    const uint4* t4 = (const uint4*)tails;
    const uint4* r4 = (const uint4*)rels;

    for (int t = 0; t < TT; t++) {
        const int tl = t * LL + l;
        if (tid == 0) {
            const float* wr = w + tl * NRELS;
            float mx = wr[0];
            for (int r = 1; r < NRELS; r++) mx = fmaxf(mx, wr[r]);
            float ex[NRELS], s = 0.f;
            for (int r = 0; r < NRELS; r++) { ex[r] = expf(wr[r] - mx); s += ex[r]; }
            float inv = 1.f / s;
            for (int r = 0; r < NRELS; r++) wrow[r] = ex[r] * inv;
        }
        if (tid >= 64 && tid < 64 + NRELS - 1)
            hp[tid - 64] = clip01(h[tl * (NRELS - 1) + (tid - 64)] / TAU1);
        if (tid >= 128 && tid < 128 + KT)
            htpL[tid - 128] = clip01(h_type[tl * KT + (tid - 128)] / TAU1);
        __syncthreads();

        if (t == 0) {
            for (int i = tid; i < NTRI / 4; i += NT) {
                uint4 hh = h4[i], ttv = t4[i], rr = r4[i];
#pragma unroll
                for (int k = 0; k < 4; k++) {
                    unsigned int hd = (k == 0) ? hh.x : (k == 1) ? hh.y : (k == 2) ? hh.z : hh.w;
                    unsigned int ta = (k == 0) ? ttv.x : (k == 1) ? ttv.y : (k == 2) ? ttv.z : ttv.w;
                    unsigned int r  = (k == 0) ? rr.x : (k == 1) ? rr.y : (k == 2) ? rr.z : rr.w;
                    if (r < NRELS - 1) atomicOr(&mask_s[ta], 1u << r);  // hidden_base flags
                    if ((int)hd == ent_b) {
                        atomicAdd(&acc[ta], wrow[r]);
                        atomicOr(&relflag, 1u << r);
                    }
                }
            }
        } else {
            for (int i = tid; i < NTRI / 4; i += NT) {
                uint4 hh = h4[i], ttv = t4[i], rr = r4[i];
#pragma unroll
                for (int k = 0; k < 4; k++) {
                    unsigned int hd = (k == 0) ? hh.x : (k == 1) ? hh.y : (k == 2) ? hh.z : hh.w;
                    float pv = prev[hd];
                    if (pv != 0.f) {
                        unsigned int ta = (k == 0) ? ttv.x : (k == 1) ? ttv.y : (k == 2) ? ttv.z : ttv.w;
                        unsigned int r  = (k == 0) ? rr.x : (k == 1) ? rr.y : (k == 2) ? rr.z : rr.w;
                        atomicAdd(&acc[ta], pv * wrow[r]);
                    }
                }
            }
        }
        __syncthreads();

        const float a = clip01(alpha[tl] / TAU1);
        const float bb = clip01(beta[tl] / TAU1);
        const float base = 1.f - clip01(a + bb);

        if (t == 0 && tid == 0) {
            unsigned int fl = relflag;
            float hxlin = 0.f;
            for (int i = 0; i < NRELS - 1; i++) {
                int pi = (i < 12) ? (12 + i) : (i - 12);  // concat(hx_raw[:,12:24], hx_raw[:,0:12])
                if ((fl >> pi) & 1u) hxlin += clip01(h_x[l * (NRELS - 1) + i] / TAU1);
            }
            float htx = clip01(h_x_type[l * KT + tidx_s[ent_b]] / TAU1);
            float ax = clip01(alpha_x[l] / TAU1), bx = clip01(beta_x[l] / TAU1);
            extra_s = clip01(a * htx + bb * hxlin) + (1.f - clip01(ax + bx));
        }
        __syncthreads();

        const float extra = (t == 0) ? extra_s : 1.f;

        if (t < TT - 1) {
            for (int e = tid; e < E; e += NT) {
                unsigned int m = mask_s[e];
                float dot = 0.f;
#pragma unroll
                for (int i = 0; i < NRELS - 1; i++) dot += ((m >> i) & 1u) ? hp[i] : 0.f;
                float he = clip01(a * htpL[tidx_s[e]] + bb * dot) + base;
                prev[e] = acc[e] * he * extra;
                acc[e] = 0.f;
            }
        } else {
            float tw = tanhf(weight[l]);
            for (int e = tid; e < E; e += NT) {
                unsigned int m = mask_s[e];
                float dot = 0.f;
#pragma unroll
                for (int i = 0; i < NRELS - 1; i++) dot += ((m >> i) & 1u) ? hp[i] : 0.f;
                float he = clip01(a * htpL[tidx_s[e]] + bb * dot) + base;
                atomicAdd(&out[b * E + e], acc[e] * he * tw);
            }
        }
        __syncthreads();
    }
}

extern "C" void kernel_launch(void* const* d_in, const int* in_sizes, int n_in,
                              void* d_out, int out_size, void* d_ws, size_t ws_size,
                              hipStream_t stream) {
    const float* input_x  = (const float*)d_in[0];
    const float* type_mat = (const float*)d_in[1];
    const float* e2triple = (const float*)d_in[2];
    const float* triple2e = (const float*)d_in[3];
    const float* triple2r = (const float*)d_in[4];
    const float* w        = (const float*)d_in[5];
    const float* weight   = (const float*)d_in[6];
    const float* h        = (const float*)d_in[7];
    const float* h_x      = (const float*)d_in[8];
    const float* h_type   = (const float*)d_in[9];
    const float* h_x_type = (const float*)d_in[10];
    const float* alpha    = (const float*)d_in[11];
    const float* beta     = (const float*)d_in[12];
    const float* alpha_x  = (const float*)d_in[13];
    const float* beta_x   = (const float*)d_in[14];
    (void)in_sizes; (void)n_in; (void)out_size; (void)ws_size;

    // All ws arrays are fully written by extract_all before mega_prop reads
    // them (one-hot structure => every slot has exactly one writer), so no
    // memset node is needed despite the 0xAA poison.
    char* ws = (char*)d_ws;
    int* heads = (int*)ws;                         // NTRI
    int* tails = heads + ((NTRI + 63) & ~63);      // NTRI
    int* rels  = tails + ((NTRI + 63) & ~63);      // NTRI
    int* ent   = rels + ((NTRI + 63) & ~63);       // B
    int* tidx  = ent + 64;                         // E

    extract_all<<<XBLK, XTHR, 0, stream>>>((const f32x4*)e2triple, (const f32x4*)triple2e,
                                           (const float4*)triple2r, (const float4*)input_x,
                                           (const float4*)type_mat,
                                           heads, tails, rels, ent, tidx, (float4*)d_out);

    mega_prop<<<B * LL, 512, 0, stream>>>(heads, tails, rels, ent, tidx, w, h, h_type,
                                          alpha, beta, h_x, h_x_type, alpha_x, beta_x,
                                          weight, (float*)d_out);
}